// Round 20
// baseline (40.051 us; speedup 1.0000x reference)
//
#include <hip/hip_runtime.h>

typedef unsigned int u32;
typedef unsigned short u16;
typedef __attribute__((ext_vector_type(8))) _Float16 f16x8;
typedef __attribute__((ext_vector_type(4))) _Float16 f16x4;
typedef __attribute__((ext_vector_type(4))) float f32x4;

namespace {

constexpr int kH = 48, kW = 48, kHW = kH * kW;     // 2304
constexpr int kC = 256;
constexpr int kB = 2;
constexpr int kM = kB * kHW;                        // 4608 GEMM rows
constexpr int kPH = 54, kPW = 56, kPP = kPH * kPW;  // padded kv grid (3024)
constexpr float kInvTemp = 0.17677669529663687f;    // 1/sqrt(32)

constexpr size_t KPAD_U16 = (size_t)16 * kPP * 32;  // 1,548,288 u16 per mat
constexpr size_t QBF_U16 = (size_t)kM * kC;         // 1,179,648 u16
// border zeroing: 720 border pixels/plane x 16 planes x 2 mats x 4 uint4
constexpr int kZeroTasks = 720 * 16 * 2 * 4;        // 92,160
constexpr int kZeroPerBlk = 54;                     // 1728 qkv blocks x 54 >= 92160

__device__ __forceinline__ u32 pack2h(float lo, float hi) {
  return __builtin_bit_cast(u32, __builtin_amdgcn_cvt_pkrtz(lo, hi));
}
__device__ __forceinline__ u16 f2h(float f) {
  return __builtin_bit_cast(u16, (_Float16)f);
}
__device__ __forceinline__ float f4e(const float4 v, int i) {
  return (i == 0) ? v.x : (i == 1) ? v.y : (i == 2) ? v.z : v.w;
}

// ---------------------------------------------------------------------------
// Fused QKV GEMM, 32x64 tiles -> 1728 blocks (R7/R15-proven, verbatim).
// ---------------------------------------------------------------------------
__global__ __launch_bounds__(256) void gemm_qkv_kernel(
    const float* __restrict__ q, const float* __restrict__ k,
    const float* __restrict__ v, const float* __restrict__ Wq,
    const float* __restrict__ Wk, const float* __restrict__ Wv,
    u16* __restrict__ qbf, u16* __restrict__ kpad, u16* __restrict__ vpad) {
  __shared__ __align__(16) u16 As[32 * 64];
  __shared__ __align__(16) u16 Bs[64 * 64];
  const int t = threadIdx.x;

  // ---- border zeroing (1.5 MB total across the 1728 blocks) ----
  {
    const int bid = (blockIdx.z * 4 + blockIdx.y) * 144 + blockIdx.x;
    const int T = bid * kZeroPerBlk + t;
    if (t < kZeroPerBlk && T < kZeroTasks) {
      const int ch = T & 3, rest = T >> 2;  // rest < 23040
      const int pm = rest / 720, bi = rest - pm * 720;
      int y, x;
      if (bi < 336) {  // full rows 0,1,2,51,52,53
        const int r = bi / 56, c = bi - (bi / 56) * 56;
        y = (r < 3) ? r : 48 + r;
        x = c;
      } else {  // rows 3..50, cols {0,1,2,51..55}
        const int r = (bi - 336) >> 3, c = (bi - 336) & 7;
        y = 3 + r;
        x = (c < 3) ? c : c + 48;
      }
      u16* pb = (pm >= 16) ? vpad : kpad;
      const uint4 zz = {0u, 0u, 0u, 0u};
      *(uint4*)&pb[((size_t)(pm & 15) * kPP + y * kPW + x) * 32 + ch * 8] = zz;
    }
  }

  const int z = blockIdx.z;
  const float* X = (z == 0) ? q : (z == 1) ? k : v;
  const float* Wm = (z == 0) ? Wq : (z == 1) ? Wk : Wv;
  const int m0 = blockIdx.x * 32, n0 = blockIdx.y * 64;
  const int bb = m0 / kHW, p0 = m0 - bb * kHW;  // 2304%32==0: no straddle
  const int l = t & 63, w = t >> 6, wm = w >> 1, wn = w & 1;
  const int mq = t & 7, kp = t >> 3;  // kp in [0,32): c-pair index

  f32x4 acc[2];
#pragma unroll
  for (int nf = 0; nf < 2; ++nf) acc[nf] = (f32x4){0.f, 0.f, 0.f, 0.f};

  for (int kt = 0; kt < 4; ++kt) {
    const int k0 = kt * 64;
    if (kt) __syncthreads();
    {
      const float* ab =
          X + ((size_t)(bb * kC + k0 + kp * 2)) * kHW + p0 + mq * 4;
      const float4 r0 = *(const float4*)(ab);
      const float4 r1 = *(const float4*)(ab + kHW);
#pragma unroll
      for (int i = 0; i < 4; ++i) {
        const int ml = mq * 4 + i;
        const u32 pk = pack2h(f4e(r0, i), f4e(r1, i));
        const int bo = (kp * 4) ^ ((ml & 7) << 4);
        *(u32*)&As[ml * 64 + (bo >> 1)] = pk;
      }
    }
#pragma unroll
    for (int j = 0; j < 4; ++j) {
      const int task2 = t + j * 256;
      const int rr = task2 >> 4, f4i = task2 & 15;
      const float4 val =
          *(const float4*)&Wm[(size_t)(n0 + rr) * kC + k0 + f4i * 4];
      uint2 pk;
      pk.x = pack2h(val.x, val.y);
      pk.y = pack2h(val.z, val.w);
      const int bo = (f4i * 8) ^ ((rr & 7) << 4);
      *(uint2*)&Bs[rr * 64 + (bo >> 1)] = pk;
    }
    __syncthreads();
#pragma unroll
    for (int ks = 0; ks < 2; ++ks) {
      const int bo = ks * 64 + ((l >> 4) << 4);
      const int rowa = wm * 16 + (l & 15);
      const f16x8 a =
          *(const f16x8*)&As[rowa * 64 + ((bo ^ ((rowa & 7) << 4)) >> 1)];
      f16x8 bfr[2];
#pragma unroll
      for (int nf = 0; nf < 2; ++nf) {
        const int row = wn * 32 + nf * 16 + (l & 15);
        bfr[nf] =
            *(const f16x8*)&Bs[row * 64 + ((bo ^ ((row & 7) << 4)) >> 1)];
      }
#pragma unroll
      for (int nf = 0; nf < 2; ++nf)
        acc[nf] = __builtin_amdgcn_mfma_f32_16x16x32_f16(a, bfr[nf], acc[nf],
                                                         0, 0, 0);
    }
  }

  u16* pd = (z == 1) ? kpad : vpad;
#pragma unroll
  for (int nf = 0; nf < 2; ++nf)
#pragma unroll
    for (int i = 0; i < 4; ++i) {
      const int m = m0 + wm * 16 + ((l >> 4) << 2) + i;
      const int o = n0 + wn * 32 + nf * 16 + (l & 15);
      const float val = acc[nf][i];
      if (z == 0) {
        qbf[(size_t)m * kC + o] = f2h(val);
      } else {
        const int p = m - bb * kHW;
        const int y = p / kW, x = p - (p / kW) * kW;
        pd[((size_t)(bb * 8 + (o >> 5)) * kPP + (y + 3) * kPW + (x + 3)) * 32 +
           (o & 31)] = f2h(val);
      }
    }
}

// ---------------------------------------------------------------------------
// Attention v5: 4x8-px tiles, 8 lanes/px -> 1152 blocks (all co-resident,
// ZERO scheduler tail vs attn4's 9-units-on-8-slots drain). Halo overhead
// 6.25 -> 4.4 halo-px/px and q redundancy 16x -> 8x: attn global reads
// 66 -> 39 MB. Cost: steady-state 32 -> ~18 waves/CU — this is the
// redundancy-vs-marginal-occupancy experiment. QK: n = nn*8+sub (7 rounds),
// softmax over 8-lane groups (3 shfls); PV: lane owns 4 ch, weights via
// s_w broadcast (conflict-free: row stride 52 words, gcd(52,32) spread).
// ---------------------------------------------------------------------------
__global__ __launch_bounds__(256) void attn5_kernel(
    const u16* __restrict__ qbf, const u16* __restrict__ kpad,
    const u16* __restrict__ vpad, u16* __restrict__ att) {
  __shared__ __align__(16) u16 kv_[2 * 140 * 40];  // 22.4 KB: k then v halo
  __shared__ float s_w[32][52];                    // 6.65 KB softmax weights

  const int t = threadIdx.x;
  const int bid = blockIdx.x;
  const int g = bid & 7, i = bid >> 3;        // g = XCD slot, i in [0,144)
  const int bh = g * 2 + (i >= 72 ? 1 : 0);   // bh pair per XCD
  const int tile = (i >= 72) ? i - 72 : i;    // [0,72)
  const int tyi = tile / 6, txi = tile - tyi * 6;  // 12 rows x 6 cols
  const int y0 = tyi * 4, x0 = txi * 8;
  const int b = bh >> 3, h = bh & 7;
  const int px = t >> 3, sub = t & 7;   // 32 px x 8 lanes
  const int py = px >> 3, pxx = px & 7; // 4 x 8 pixel tile
  const int gp = (y0 + py) * kW + (x0 + pxx);
  const int hpbase = py * 14 + pxx;

  // ---- stage k+v 10x14 halo: 1120 uint4 tasks over 256 threads ----
  const size_t plane = (size_t)bh * kPP;
  for (int task = t; task < 1120; task += 256) {
    const int mat = task >= 560;
    const int rem = task - mat * 560;
    const int hp = rem >> 2, c8 = rem & 3;
    const int hy = hp / 14, hx = hp - hy * 14;
    const size_t src = (plane + (y0 + hy) * kPW + (x0 + hx)) * 32 + c8 * 8;
    *(uint4*)&kv_[mat * 5600 + hp * 40 + c8 * 8] =
        *(const uint4*)&(mat ? vpad : kpad)[src];
  }
  // q: full 32 ch in f16 regs (8x redundant per px; coalesced broadcast)
  f16x8 qh[4];
  {
    const size_t qb = ((size_t)(b * kHW + gp)) * kC + h * 32;
    qh[0] = *(const f16x8*)&qbf[qb + 0];
    qh[1] = *(const f16x8*)&qbf[qb + 8];
    qh[2] = *(const f16x8*)&qbf[qb + 16];
    qh[3] = *(const f16x8*)&qbf[qb + 24];
  }
  __syncthreads();  // halo staged

  // ---- QK: lane handles neighbors n = nn*8 + sub; 4 indep fma chains ----
  float sc[7];
  float pm = -1e30f;
#pragma unroll
  for (int nn = 0; nn < 7; ++nn) {
    const int n = nn * 8 + sub;
    float s = -1e30f;
    if (n < 49) {
      const int ky = (n * 147) >> 10, kx = n - ky * 7;  // n/7, n%7 (n<56 ok)
      const u16* kr = &kv_[(hpbase + ky * 14 + kx) * 40];
      float dd[4];
#pragma unroll
      for (int c8 = 0; c8 < 4; ++c8) {
        const f16x8 kk = *(const f16x8*)&kr[c8 * 8];
        float d = 0.f;
#pragma unroll
        for (int j = 0; j < 8; ++j) d += (float)kk[j] * (float)qh[c8][j];
        dd[c8] = d;
      }
      s = ((dd[0] + dd[1]) + (dd[2] + dd[3])) * kInvTemp;
    }
    sc[nn] = s;
    pm = fmaxf(pm, s);
  }
  // softmax across the 8-lane px group
  pm = fmaxf(pm, __shfl_xor(pm, 1));
  pm = fmaxf(pm, __shfl_xor(pm, 2));
  pm = fmaxf(pm, __shfl_xor(pm, 4));
  float zs = 0.f;
#pragma unroll
  for (int nn = 0; nn < 7; ++nn) {
    const int n = nn * 8 + sub;
    const float e = __expf(sc[nn] - pm);  // invalid n: exp(-huge) = 0
    zs += e;
    if (n < 49) s_w[px][n] = e;  // same-wave producer/consumer
  }
  zs += __shfl_xor(zs, 1);
  zs += __shfl_xor(zs, 2);
  zs += __shfl_xor(zs, 4);
  const float rinv = 1.0f / zs;

  // ---- PV: lane owns channels [sub*4, sub*4+4); even/odd-n chain pairs ----
  float oa[4] = {0.f, 0.f, 0.f, 0.f}, ob[4] = {0.f, 0.f, 0.f, 0.f};
#pragma unroll
  for (int n = 0; n < 49; ++n) {
    const int ky = n / 7, kx = n % 7;  // compile-time
    const int hp = hpbase + ky * 14 + kx;
    const float wgt = s_w[px][n];  // 8-lane broadcast
    const uint2 vv = *(const uint2*)&kv_[5600 + hp * 40 + sub * 4];
    const f16x4 v4 = __builtin_bit_cast(f16x4, vv);
    if (n & 1) {
#pragma unroll
      for (int c = 0; c < 4; ++c) ob[c] += wgt * (float)v4[c];
    } else {
#pragma unroll
      for (int c = 0; c < 4; ++c) oa[c] += wgt * (float)v4[c];
    }
  }
  uint2 outv;
  outv.x = pack2h((oa[0] + ob[0]) * rinv, (oa[1] + ob[1]) * rinv);
  outv.y = pack2h((oa[2] + ob[2]) * rinv, (oa[3] + ob[3]) * rinv);
  *(uint2*)&att[((size_t)(b * kHW + gp)) * kC + h * 32 + sub * 4] = outv;
}

// ---------------------------------------------------------------------------
// FC GEMM: BM=32 x BN=32 -> 1152 blocks (R15-proven, verbatim; fp32 Wfc).
// ---------------------------------------------------------------------------
__global__ __launch_bounds__(256) void gemm_fc_kernel(
    const u16* __restrict__ att, const float* __restrict__ Wfc,
    const float* __restrict__ Res, float* __restrict__ Out) {
  __shared__ __align__(16) u16 As[32 * 64];  // Wfc rows (o)
  __shared__ __align__(16) u16 Bs[32 * 64];  // att rows (pixels)
  const int t = threadIdx.x;
  const int q0 = blockIdx.x * 32;  // pixel block (global over 4608)
  const int o0 = blockIdx.y * 32;
  const int bb = q0 / kHW, p0 = q0 - bb * kHW;  // 2304%32==0
  const int l = t & 63, w = t >> 6, wm = w >> 1, wn = w & 1;

  f32x4 acc = {0.f, 0.f, 0.f, 0.f};

  for (int kt = 0; kt < 4; ++kt) {
    const int k0 = kt * 64;
    if (kt) __syncthreads();
#pragma unroll
    for (int j = 0; j < 2; ++j) {  // As <- Wfc (cvt): 32 rows x 16 float4
      const int task = t + j * 256;
      const int rr = task >> 4, f4i = task & 15;
      const float4 val =
          *(const float4*)&Wfc[(size_t)(o0 + rr) * kC + k0 + f4i * 4];
      uint2 pk;
      pk.x = pack2h(val.x, val.y);
      pk.y = pack2h(val.z, val.w);
      const int bo = (f4i * 8) ^ ((rr & 7) << 4);
      *(uint2*)&As[rr * 64 + (bo >> 1)] = pk;
    }
    {  // Bs <- att (f16): 32 rows x 8 uint4 = 256 tasks
      const int rr = t >> 3, ch = t & 7;
      const uint4 val =
          *(const uint4*)&att[(size_t)(q0 + rr) * kC + k0 + ch * 8];
      const int bo = (ch * 16) ^ ((rr & 7) << 4);
      *(uint4*)&Bs[rr * 64 + (bo >> 1)] = val;
    }
    __syncthreads();
#pragma unroll
    for (int ks = 0; ks < 2; ++ks) {
      const int bo = ks * 64 + ((l >> 4) << 4);
      const int rowa = wm * 16 + (l & 15);
      const f16x8 a =
          *(const f16x8*)&As[rowa * 64 + ((bo ^ ((rowa & 7) << 4)) >> 1)];
      const int rowb = wn * 16 + (l & 15);
      const f16x8 bfr =
          *(const f16x8*)&Bs[rowb * 64 + ((bo ^ ((rowb & 7) << 4)) >> 1)];
      acc = __builtin_amdgcn_mfma_f32_16x16x32_f16(a, bfr, acc, 0, 0, 0);
    }
  }
#pragma unroll
  for (int i = 0; i < 4; ++i) {
    const int o = o0 + wm * 16 + ((l >> 4) << 2) + i;
    const int p = p0 + wn * 16 + (l & 15);
    const size_t addr = ((size_t)(bb * kC + o)) * kHW + p;
    Out[addr] = acc[i] + Res[addr];
  }
}

}  // namespace

extern "C" void kernel_launch(void* const* d_in, const int* in_sizes, int n_in,
                              void* d_out, int out_size, void* d_ws,
                              size_t ws_size, hipStream_t stream) {
  const float* q = (const float*)d_in[0];
  const float* k = (const float*)d_in[1];
  const float* v = (const float*)d_in[2];
  const float* Wq = (const float*)d_in[3];
  const float* Wk = (const float*)d_in[4];
  const float* Wv = (const float*)d_in[5];
  const float* Wfc = (const float*)d_in[6];
  float* out = (float*)d_out;

  u16* ws16 = (u16*)d_ws;
  u16* kpad = ws16;
  u16* vpad = ws16 + KPAD_U16;
  u16* qbf = ws16 + 2 * KPAD_U16;
  u16* att = qbf + QBF_U16;

  gemm_qkv_kernel<<<dim3(kM / 32, kC / 64, 3), 256, 0, stream>>>(
      q, k, v, Wq, Wk, Wv, qbf, kpad, vpad);

  // 1152 blocks (4-5/CU, ALL co-resident, no tail): (b,h,4x8 tile) each.
  attn5_kernel<<<dim3(1152), 256, 0, stream>>>(qbf, kpad, vpad, att);

  // 1152 blocks (4.5 waves/SIMD).
  gemm_fc_kernel<<<dim3(kM / 32, kC / 32), 256, 0, stream>>>(att, Wfc, q,
                                                             out);
}

// Round 21
// 36.593 us; speedup vs baseline: 1.0945x; 1.0945x over previous
//
#include <hip/hip_runtime.h>

typedef unsigned int u32;
typedef unsigned short u16;
typedef __attribute__((ext_vector_type(8))) _Float16 f16x8;
typedef __attribute__((ext_vector_type(2))) _Float16 f16x2;
typedef __attribute__((ext_vector_type(4))) float f32x4;

namespace {

constexpr int kH = 48, kW = 48, kHW = kH * kW;     // 2304
constexpr int kC = 256;
constexpr int kB = 2;
constexpr int kM = kB * kHW;                        // 4608 GEMM rows
constexpr int kPH = 54, kPW = 56, kPP = kPH * kPW;  // padded kv grid (3024)
constexpr float kInvTemp = 0.17677669529663687f;    // 1/sqrt(32)

constexpr size_t KPAD_U16 = (size_t)16 * kPP * 32;  // 1,548,288 u16 per mat
constexpr size_t QBF_U16 = (size_t)kM * kC;         // 1,179,648 u16
// border zeroing: 720 border pixels/plane x 16 planes x 2 mats x 4 uint4
constexpr int kZeroTasks = 720 * 16 * 2 * 4;        // 92,160
constexpr int kZeroPerBlk = 54;                     // 1728 qkv blocks x 54 >= 92160

__device__ __forceinline__ u32 pack2h(float lo, float hi) {
  return __builtin_bit_cast(u32, __builtin_amdgcn_cvt_pkrtz(lo, hi));
}
__device__ __forceinline__ u16 f2h(float f) {
  return __builtin_bit_cast(u16, (_Float16)f);
}
__device__ __forceinline__ float f4e(const float4 v, int i) {
  return (i == 0) ? v.x : (i == 1) ? v.y : (i == 2) ? v.z : v.w;
}

// ---------------------------------------------------------------------------
// Fused QKV GEMM, 32x64 tiles -> 1728 blocks (R7/R15-proven, verbatim).
// ---------------------------------------------------------------------------
__global__ __launch_bounds__(256) void gemm_qkv_kernel(
    const float* __restrict__ q, const float* __restrict__ k,
    const float* __restrict__ v, const float* __restrict__ Wq,
    const float* __restrict__ Wk, const float* __restrict__ Wv,
    u16* __restrict__ qbf, u16* __restrict__ kpad, u16* __restrict__ vpad) {
  __shared__ __align__(16) u16 As[32 * 64];
  __shared__ __align__(16) u16 Bs[64 * 64];
  const int t = threadIdx.x;

  // ---- border zeroing (1.5 MB total across the 1728 blocks) ----
  {
    const int bid = (blockIdx.z * 4 + blockIdx.y) * 144 + blockIdx.x;
    const int T = bid * kZeroPerBlk + t;
    if (t < kZeroPerBlk && T < kZeroTasks) {
      const int ch = T & 3, rest = T >> 2;  // rest < 23040
      const int pm = rest / 720, bi = rest - pm * 720;
      int y, x;
      if (bi < 336) {  // full rows 0,1,2,51,52,53
        const int r = bi / 56, c = bi - (bi / 56) * 56;
        y = (r < 3) ? r : 48 + r;
        x = c;
      } else {  // rows 3..50, cols {0,1,2,51..55}
        const int r = (bi - 336) >> 3, c = (bi - 336) & 7;
        y = 3 + r;
        x = (c < 3) ? c : c + 48;
      }
      u16* pb = (pm >= 16) ? vpad : kpad;
      const uint4 zz = {0u, 0u, 0u, 0u};
      *(uint4*)&pb[((size_t)(pm & 15) * kPP + y * kPW + x) * 32 + ch * 8] = zz;
    }
  }

  const int z = blockIdx.z;
  const float* X = (z == 0) ? q : (z == 1) ? k : v;
  const float* Wm = (z == 0) ? Wq : (z == 1) ? Wk : Wv;
  const int m0 = blockIdx.x * 32, n0 = blockIdx.y * 64;
  const int bb = m0 / kHW, p0 = m0 - bb * kHW;  // 2304%32==0: no straddle
  const int l = t & 63, w = t >> 6, wm = w >> 1, wn = w & 1;
  const int mq = t & 7, kp = t >> 3;  // kp in [0,32): c-pair index

  f32x4 acc[2];
#pragma unroll
  for (int nf = 0; nf < 2; ++nf) acc[nf] = (f32x4){0.f, 0.f, 0.f, 0.f};

  for (int kt = 0; kt < 4; ++kt) {
    const int k0 = kt * 64;
    if (kt) __syncthreads();
    {
      const float* ab =
          X + ((size_t)(bb * kC + k0 + kp * 2)) * kHW + p0 + mq * 4;
      const float4 r0 = *(const float4*)(ab);
      const float4 r1 = *(const float4*)(ab + kHW);
#pragma unroll
      for (int i = 0; i < 4; ++i) {
        const int ml = mq * 4 + i;
        const u32 pk = pack2h(f4e(r0, i), f4e(r1, i));
        const int bo = (kp * 4) ^ ((ml & 7) << 4);
        *(u32*)&As[ml * 64 + (bo >> 1)] = pk;
      }
    }
#pragma unroll
    for (int j = 0; j < 4; ++j) {
      const int task2 = t + j * 256;
      const int rr = task2 >> 4, f4i = task2 & 15;
      const float4 val =
          *(const float4*)&Wm[(size_t)(n0 + rr) * kC + k0 + f4i * 4];
      uint2 pk;
      pk.x = pack2h(val.x, val.y);
      pk.y = pack2h(val.z, val.w);
      const int bo = (f4i * 8) ^ ((rr & 7) << 4);
      *(uint2*)&Bs[rr * 64 + (bo >> 1)] = pk;
    }
    __syncthreads();
#pragma unroll
    for (int ks = 0; ks < 2; ++ks) {
      const int bo = ks * 64 + ((l >> 4) << 4);
      const int rowa = wm * 16 + (l & 15);
      const f16x8 a =
          *(const f16x8*)&As[rowa * 64 + ((bo ^ ((rowa & 7) << 4)) >> 1)];
      f16x8 bfr[2];
#pragma unroll
      for (int nf = 0; nf < 2; ++nf) {
        const int row = wn * 32 + nf * 16 + (l & 15);
        bfr[nf] =
            *(const f16x8*)&Bs[row * 64 + ((bo ^ ((row & 7) << 4)) >> 1)];
      }
#pragma unroll
      for (int nf = 0; nf < 2; ++nf)
        acc[nf] = __builtin_amdgcn_mfma_f32_16x16x32_f16(a, bfr[nf], acc[nf],
                                                         0, 0, 0);
    }
  }

  u16* pd = (z == 1) ? kpad : vpad;
#pragma unroll
  for (int nf = 0; nf < 2; ++nf)
#pragma unroll
    for (int i = 0; i < 4; ++i) {
      const int m = m0 + wm * 16 + ((l >> 4) << 2) + i;
      const int o = n0 + wn * 32 + nf * 16 + (l & 15);
      const float val = acc[nf][i];
      if (z == 0) {
        qbf[(size_t)m * kC + o] = f2h(val);
      } else {
        const int p = m - bb * kHW;
        const int y = p / kW, x = p - (p / kW) * kW;
        pd[((size_t)(bb * 8 + (o >> 5)) * kPP + (y + 3) * kPW + (x + 3)) * 32 +
           (o & 31)] = f2h(val);
      }
    }
}

// ---------------------------------------------------------------------------
// Attention v4b (R15/R19-proven best, verbatim): 2304 blocks (one
// (b,h,4x4-px) each), natural VGPR (5 waves/SIMD), narrow PV with
// even/odd-n chain pairs, ILP'd QK (4 indep 8-fma chains), XCD decode.
// Closed axes: (256,6) spills (+6.1, R18); wide-PV (+0.6, R17);
// f16-W pre-cvt dispatch (+1.2, R16); 4x8 tiles @ lower occupancy
// (+3.4, R20). Occupancy > redundancy in this regime (R14, R20).
// ---------------------------------------------------------------------------
__global__ __launch_bounds__(256) void attn4_kernel(
    const u16* __restrict__ qbf, const u16* __restrict__ kpad,
    const u16* __restrict__ vpad, u16* __restrict__ att) {
  __shared__ __align__(16) u16 kv_[2 * 100 * 40];  // 16 KB: k then v halo
  __shared__ float s_w[16][52];                    // 3.3 KB softmax weights

  const int t = threadIdx.x;
  const int bid = blockIdx.x;
  const int g = bid & 7, i = bid >> 3;        // g = XCD slot, i in [0,288)
  const int bh = g * 2 + (i >= 144 ? 1 : 0);  // bh pair per XCD
  const int tile = (i >= 144) ? i - 144 : i;
  const int tyi = tile / 12, txi = tile - tyi * 12;
  const int y0 = tyi * 4, x0 = txi * 4;
  const int b = bh >> 3, h = bh & 7;
  const int px = t >> 4, sub = t & 15;  // 16 px x 16 lanes
  const int py = px >> 2, pxx = px & 3;
  const int gp = (y0 + py) * kW + (x0 + pxx);
  const int hpbase = py * 10 + pxx;

  // ---- stage k+v 10x10 halo: 800 uint4 tasks over 256 threads ----
  const size_t plane = (size_t)bh * kPP;
  for (int task = t; task < 800; task += 256) {
    const int mat = task >= 400;
    const int rem = task - mat * 400;
    const int hp = rem >> 2, c8 = rem & 3;
    const int hy = hp / 10, hx = hp - hy * 10;
    const size_t src = (plane + (y0 + hy) * kPW + (x0 + hx)) * 32 + c8 * 8;
    *(uint4*)&kv_[mat * 4000 + hp * 40 + c8 * 8] =
        *(const uint4*)&(mat ? vpad : kpad)[src];
  }
  // q: full 32 ch in f16 regs (redundant across the 16 lanes of a px; L1)
  f16x8 qh[4];
  {
    const size_t qb = ((size_t)(b * kHW + gp)) * kC + h * 32;
    qh[0] = *(const f16x8*)&qbf[qb + 0];
    qh[1] = *(const f16x8*)&qbf[qb + 8];
    qh[2] = *(const f16x8*)&qbf[qb + 16];
    qh[3] = *(const f16x8*)&qbf[qb + 24];
  }
  __syncthreads();  // halo staged

  // ---- QK: lane handles neighbors n = nn*16 + sub; 4 indep fma chains ----
  float sc[4];
  float pm = -1e30f;
#pragma unroll
  for (int nn = 0; nn < 4; ++nn) {
    const int n = nn * 16 + sub;
    float s = -1e30f;
    if (n < 49) {
      const int ky = (n * 147) >> 10, kx = n - ky * 7;  // n/7, n%7
      const u16* kr = &kv_[(hpbase + ky * 10 + kx) * 40];
      float dd[4];
#pragma unroll
      for (int c8 = 0; c8 < 4; ++c8) {
        const f16x8 kk = *(const f16x8*)&kr[c8 * 8];
        float d = 0.f;
#pragma unroll
        for (int j = 0; j < 8; ++j) d += (float)kk[j] * (float)qh[c8][j];
        dd[c8] = d;
      }
      s = ((dd[0] + dd[1]) + (dd[2] + dd[3])) * kInvTemp;
    }
    sc[nn] = s;
    pm = fmaxf(pm, s);
  }
  // softmax across the 16-lane px group
  pm = fmaxf(pm, __shfl_xor(pm, 1));
  pm = fmaxf(pm, __shfl_xor(pm, 2));
  pm = fmaxf(pm, __shfl_xor(pm, 4));
  pm = fmaxf(pm, __shfl_xor(pm, 8));
  float zs = 0.f;
#pragma unroll
  for (int nn = 0; nn < 4; ++nn) {
    const int n = nn * 16 + sub;
    const float e = __expf(sc[nn] - pm);  // invalid n: exp(-huge) = 0
    zs += e;
    if (n < 49) s_w[px][n] = e;  // same-wave producer/consumer
  }
  zs += __shfl_xor(zs, 1);
  zs += __shfl_xor(zs, 2);
  zs += __shfl_xor(zs, 4);
  zs += __shfl_xor(zs, 8);
  const float rinv = 1.0f / zs;

  // ---- PV: lane owns channels {2*sub, 2*sub+1}; even/odd-n chain pairs ----
  float oa0 = 0.f, oa1 = 0.f, ob0 = 0.f, ob1 = 0.f;
#pragma unroll
  for (int n = 0; n < 49; ++n) {
    const int ky = n / 7, kx = n % 7;  // compile-time
    const int hp = hpbase + ky * 10 + kx;
    const float wgt = s_w[px][n];  // 16-lane broadcast
    const u32 vv = *(const u32*)&kv_[4000 + hp * 40 + sub * 2];
    const f16x2 v2 = __builtin_bit_cast(f16x2, vv);
    if (n & 1) {
      ob0 += wgt * (float)v2[0];
      ob1 += wgt * (float)v2[1];
    } else {
      oa0 += wgt * (float)v2[0];
      oa1 += wgt * (float)v2[1];
    }
  }
  const float o0 = oa0 + ob0, o1 = oa1 + ob1;
  *(u32*)&att[((size_t)(b * kHW + gp)) * kC + h * 32 + sub * 2] =
      pack2h(o0 * rinv, o1 * rinv);
}

// ---------------------------------------------------------------------------
// FC GEMM: BM=32 x BN=32 -> 1152 blocks (R15-proven, verbatim; fp32 Wfc).
// ---------------------------------------------------------------------------
__global__ __launch_bounds__(256) void gemm_fc_kernel(
    const u16* __restrict__ att, const float* __restrict__ Wfc,
    const float* __restrict__ Res, float* __restrict__ Out) {
  __shared__ __align__(16) u16 As[32 * 64];  // Wfc rows (o)
  __shared__ __align__(16) u16 Bs[32 * 64];  // att rows (pixels)
  const int t = threadIdx.x;
  const int q0 = blockIdx.x * 32;  // pixel block (global over 4608)
  const int o0 = blockIdx.y * 32;
  const int bb = q0 / kHW, p0 = q0 - bb * kHW;  // 2304%32==0
  const int l = t & 63, w = t >> 6, wm = w >> 1, wn = w & 1;

  f32x4 acc = {0.f, 0.f, 0.f, 0.f};

  for (int kt = 0; kt < 4; ++kt) {
    const int k0 = kt * 64;
    if (kt) __syncthreads();
#pragma unroll
    for (int j = 0; j < 2; ++j) {  // As <- Wfc (cvt): 32 rows x 16 float4
      const int task = t + j * 256;
      const int rr = task >> 4, f4i = task & 15;
      const float4 val =
          *(const float4*)&Wfc[(size_t)(o0 + rr) * kC + k0 + f4i * 4];
      uint2 pk;
      pk.x = pack2h(val.x, val.y);
      pk.y = pack2h(val.z, val.w);
      const int bo = (f4i * 8) ^ ((rr & 7) << 4);
      *(uint2*)&As[rr * 64 + (bo >> 1)] = pk;
    }
    {  // Bs <- att (f16): 32 rows x 8 uint4 = 256 tasks
      const int rr = t >> 3, ch = t & 7;
      const uint4 val =
          *(const uint4*)&att[(size_t)(q0 + rr) * kC + k0 + ch * 8];
      const int bo = (ch * 16) ^ ((rr & 7) << 4);
      *(uint4*)&Bs[rr * 64 + (bo >> 1)] = val;
    }
    __syncthreads();
#pragma unroll
    for (int ks = 0; ks < 2; ++ks) {
      const int bo = ks * 64 + ((l >> 4) << 4);
      const int rowa = wm * 16 + (l & 15);
      const f16x8 a =
          *(const f16x8*)&As[rowa * 64 + ((bo ^ ((rowa & 7) << 4)) >> 1)];
      const int rowb = wn * 16 + (l & 15);
      const f16x8 bfr =
          *(const f16x8*)&Bs[rowb * 64 + ((bo ^ ((rowb & 7) << 4)) >> 1)];
      acc = __builtin_amdgcn_mfma_f32_16x16x32_f16(a, bfr, acc, 0, 0, 0);
    }
  }
#pragma unroll
  for (int i = 0; i < 4; ++i) {
    const int o = o0 + wm * 16 + ((l >> 4) << 2) + i;
    const int p = p0 + wn * 16 + (l & 15);
    const size_t addr = ((size_t)(bb * kC + o)) * kHW + p;
    Out[addr] = acc[i] + Res[addr];
  }
}

}  // namespace

extern "C" void kernel_launch(void* const* d_in, const int* in_sizes, int n_in,
                              void* d_out, int out_size, void* d_ws,
                              size_t ws_size, hipStream_t stream) {
  const float* q = (const float*)d_in[0];
  const float* k = (const float*)d_in[1];
  const float* v = (const float*)d_in[2];
  const float* Wq = (const float*)d_in[3];
  const float* Wk = (const float*)d_in[4];
  const float* Wv = (const float*)d_in[5];
  const float* Wfc = (const float*)d_in[6];
  float* out = (float*)d_out;

  u16* ws16 = (u16*)d_ws;
  u16* kpad = ws16;
  u16* vpad = ws16 + KPAD_U16;
  u16* qbf = ws16 + 2 * KPAD_U16;
  u16* att = qbf + QBF_U16;

  gemm_qkv_kernel<<<dim3(kM / 32, kC / 64, 3), 256, 0, stream>>>(
      q, k, v, Wq, Wk, Wv, qbf, kpad, vpad);

  // 2304 blocks (8 blocks/CU co-resident): one (b,h,4x4 tile), XCD-decoded.
  attn4_kernel<<<dim3(2304), 256, 0, stream>>>(qbf, kpad, vpad, att);

  // 1152 blocks (4.5 waves/SIMD).
  gemm_fc_kernel<<<dim3(kM / 32, kC / 32), 256, 0, stream>>>(att, Wfc, q,
                                                             out);
}

// Round 22
// 34.026 us; speedup vs baseline: 1.1771x; 1.0754x over previous
//
#include <hip/hip_runtime.h>

typedef unsigned int u32;
typedef unsigned short u16;
typedef __attribute__((ext_vector_type(8))) _Float16 f16x8;
typedef __attribute__((ext_vector_type(2))) _Float16 f16x2;
typedef __attribute__((ext_vector_type(4))) float f32x4;

namespace {

constexpr int kH = 48, kW = 48, kHW = kH * kW;     // 2304
constexpr int kC = 256;
constexpr int kB = 2;
constexpr int kM = kB * kHW;                        // 4608 GEMM rows
constexpr int kPH = 54, kPW = 56, kPP = kPH * kPW;  // padded kv grid (3024)
constexpr float kInvTemp = 0.17677669529663687f;    // 1/sqrt(32)

constexpr size_t KPAD_U16 = (size_t)16 * kPP * 32;  // 1,548,288 u16 per mat
constexpr size_t QBF_U16 = (size_t)kM * kC;         // 1,179,648 u16
constexpr size_t ATT_U16 = (size_t)kM * kC;
// border zeroing: 720 border pixels/plane x 16 planes x 2 mats x 4 uint4
constexpr int kZeroTasks = 720 * 16 * 2 * 4;        // 92,160
constexpr int kZeroPerBlk = 54;                     // 1728 qkv blocks x 54 >= 92160
// Wfc f16 conversion side-task: 65536 floats = 8192 uint4 outputs
constexpr int kWfcTasks = 8192;                     // 1728 blocks x 5 >= 8192

__device__ __forceinline__ u32 pack2h(float lo, float hi) {
  return __builtin_bit_cast(u32, __builtin_amdgcn_cvt_pkrtz(lo, hi));
}
__device__ __forceinline__ u16 f2h(float f) {
  return __builtin_bit_cast(u16, (_Float16)f);
}
__device__ __forceinline__ float f4e(const float4 v, int i) {
  return (i == 0) ? v.x : (i == 1) ? v.y : (i == 2) ? v.z : v.w;
}

// ---------------------------------------------------------------------------
// Fused QKV GEMM, 32x64 tiles -> 1728 blocks (R7/R15-proven).
// Side-work: border zeroing (proven) + Wfc->f16 conversion (5 tasks/block,
// rides free; fc consumes it two dispatches later — no extra launch, which
// is what sank R16's version of this idea).
// ---------------------------------------------------------------------------
__global__ __launch_bounds__(256) void gemm_qkv_kernel(
    const float* __restrict__ q, const float* __restrict__ k,
    const float* __restrict__ v, const float* __restrict__ Wq,
    const float* __restrict__ Wk, const float* __restrict__ Wv,
    const float* __restrict__ Wfc, u16* __restrict__ qbf,
    u16* __restrict__ kpad, u16* __restrict__ vpad, u16* __restrict__ wfc16) {
  __shared__ __align__(16) u16 As[32 * 64];
  __shared__ __align__(16) u16 Bs[64 * 64];
  const int t = threadIdx.x;
  const int bid = (blockIdx.z * 4 + blockIdx.y) * 144 + blockIdx.x;

  // ---- border zeroing (1.5 MB total across the 1728 blocks) ----
  {
    const int T = bid * kZeroPerBlk + t;
    if (t < kZeroPerBlk && T < kZeroTasks) {
      const int ch = T & 3, rest = T >> 2;  // rest < 23040
      const int pm = rest / 720, bi = rest - pm * 720;
      int y, x;
      if (bi < 336) {  // full rows 0,1,2,51,52,53
        const int r = bi / 56, c = bi - (bi / 56) * 56;
        y = (r < 3) ? r : 48 + r;
        x = c;
      } else {  // rows 3..50, cols {0,1,2,51..55}
        const int r = (bi - 336) >> 3, c = (bi - 336) & 7;
        y = 3 + r;
        x = (c < 3) ? c : c + 48;
      }
      u16* pb = (pm >= 16) ? vpad : kpad;
      const uint4 zz = {0u, 0u, 0u, 0u};
      *(uint4*)&pb[((size_t)(pm & 15) * kPP + y * kPW + x) * 32 + ch * 8] = zz;
    }
  }
  // ---- Wfc -> f16 (8192 uint4 tasks over 1728 blocks; threads 64..68) ----
  {
    const int j = t - 64;
    if (j >= 0 && j < 5) {
      const int T = bid * 5 + j;
      if (T < kWfcTasks) {
        const float4 a = *(const float4*)&Wfc[T * 8];
        const float4 bq = *(const float4*)&Wfc[T * 8 + 4];
        uint4 pk;
        pk.x = pack2h(a.x, a.y);
        pk.y = pack2h(a.z, a.w);
        pk.z = pack2h(bq.x, bq.y);
        pk.w = pack2h(bq.z, bq.w);
        *(uint4*)&wfc16[(size_t)T * 8] = pk;
      }
    }
  }

  const int z = blockIdx.z;
  const float* X = (z == 0) ? q : (z == 1) ? k : v;
  const float* Wm = (z == 0) ? Wq : (z == 1) ? Wk : Wv;
  const int m0 = blockIdx.x * 32, n0 = blockIdx.y * 64;
  const int bb = m0 / kHW, p0 = m0 - bb * kHW;  // 2304%32==0: no straddle
  const int l = t & 63, w = t >> 6, wm = w >> 1, wn = w & 1;
  const int mq = t & 7, kp = t >> 3;  // kp in [0,32): c-pair index

  f32x4 acc[2];
#pragma unroll
  for (int nf = 0; nf < 2; ++nf) acc[nf] = (f32x4){0.f, 0.f, 0.f, 0.f};

  for (int kt = 0; kt < 4; ++kt) {
    const int k0 = kt * 64;
    if (kt) __syncthreads();
    {
      const float* ab =
          X + ((size_t)(bb * kC + k0 + kp * 2)) * kHW + p0 + mq * 4;
      const float4 r0 = *(const float4*)(ab);
      const float4 r1 = *(const float4*)(ab + kHW);
#pragma unroll
      for (int i = 0; i < 4; ++i) {
        const int ml = mq * 4 + i;
        const u32 pk = pack2h(f4e(r0, i), f4e(r1, i));
        const int bo = (kp * 4) ^ ((ml & 7) << 4);
        *(u32*)&As[ml * 64 + (bo >> 1)] = pk;
      }
    }
#pragma unroll
    for (int j = 0; j < 4; ++j) {
      const int task2 = t + j * 256;
      const int rr = task2 >> 4, f4i = task2 & 15;
      const float4 val =
          *(const float4*)&Wm[(size_t)(n0 + rr) * kC + k0 + f4i * 4];
      uint2 pk;
      pk.x = pack2h(val.x, val.y);
      pk.y = pack2h(val.z, val.w);
      const int bo = (f4i * 8) ^ ((rr & 7) << 4);
      *(uint2*)&Bs[rr * 64 + (bo >> 1)] = pk;
    }
    __syncthreads();
#pragma unroll
    for (int ks = 0; ks < 2; ++ks) {
      const int bo = ks * 64 + ((l >> 4) << 4);
      const int rowa = wm * 16 + (l & 15);
      const f16x8 a =
          *(const f16x8*)&As[rowa * 64 + ((bo ^ ((rowa & 7) << 4)) >> 1)];
      f16x8 bfr[2];
#pragma unroll
      for (int nf = 0; nf < 2; ++nf) {
        const int row = wn * 32 + nf * 16 + (l & 15);
        bfr[nf] =
            *(const f16x8*)&Bs[row * 64 + ((bo ^ ((row & 7) << 4)) >> 1)];
      }
#pragma unroll
      for (int nf = 0; nf < 2; ++nf)
        acc[nf] = __builtin_amdgcn_mfma_f32_16x16x32_f16(a, bfr[nf], acc[nf],
                                                         0, 0, 0);
    }
  }

  u16* pd = (z == 1) ? kpad : vpad;
#pragma unroll
  for (int nf = 0; nf < 2; ++nf)
#pragma unroll
    for (int i = 0; i < 4; ++i) {
      const int m = m0 + wm * 16 + ((l >> 4) << 2) + i;
      const int o = n0 + wn * 32 + nf * 16 + (l & 15);
      const float val = acc[nf][i];
      if (z == 0) {
        qbf[(size_t)m * kC + o] = f2h(val);
      } else {
        const int p = m - bb * kHW;
        const int y = p / kW, x = p - (p / kW) * kW;
        pd[((size_t)(bb * 8 + (o >> 5)) * kPP + (y + 3) * kPW + (x + 3)) * 32 +
           (o & 31)] = f2h(val);
      }
    }
}

// ---------------------------------------------------------------------------
// Attention v4b (R15/R19-proven best, verbatim): 2304 blocks, natural VGPR,
// narrow PV with even/odd-n chain pairs, ILP'd QK, XCD decode.
// ---------------------------------------------------------------------------
__global__ __launch_bounds__(256) void attn4_kernel(
    const u16* __restrict__ qbf, const u16* __restrict__ kpad,
    const u16* __restrict__ vpad, u16* __restrict__ att) {
  __shared__ __align__(16) u16 kv_[2 * 100 * 40];  // 16 KB: k then v halo
  __shared__ float s_w[16][52];                    // 3.3 KB softmax weights

  const int t = threadIdx.x;
  const int bid = blockIdx.x;
  const int g = bid & 7, i = bid >> 3;        // g = XCD slot, i in [0,288)
  const int bh = g * 2 + (i >= 144 ? 1 : 0);  // bh pair per XCD
  const int tile = (i >= 144) ? i - 144 : i;
  const int tyi = tile / 12, txi = tile - tyi * 12;
  const int y0 = tyi * 4, x0 = txi * 4;
  const int b = bh >> 3, h = bh & 7;
  const int px = t >> 4, sub = t & 15;  // 16 px x 16 lanes
  const int py = px >> 2, pxx = px & 3;
  const int gp = (y0 + py) * kW + (x0 + pxx);
  const int hpbase = py * 10 + pxx;

  // ---- stage k+v 10x10 halo: 800 uint4 tasks over 256 threads ----
  const size_t plane = (size_t)bh * kPP;
  for (int task = t; task < 800; task += 256) {
    const int mat = task >= 400;
    const int rem = task - mat * 400;
    const int hp = rem >> 2, c8 = rem & 3;
    const int hy = hp / 10, hx = hp - hy * 10;
    const size_t src = (plane + (y0 + hy) * kPW + (x0 + hx)) * 32 + c8 * 8;
    *(uint4*)&kv_[mat * 4000 + hp * 40 + c8 * 8] =
        *(const uint4*)&(mat ? vpad : kpad)[src];
  }
  // q: full 32 ch in f16 regs (redundant across the 16 lanes of a px; L1)
  f16x8 qh[4];
  {
    const size_t qb = ((size_t)(b * kHW + gp)) * kC + h * 32;
    qh[0] = *(const f16x8*)&qbf[qb + 0];
    qh[1] = *(const f16x8*)&qbf[qb + 8];
    qh[2] = *(const f16x8*)&qbf[qb + 16];
    qh[3] = *(const f16x8*)&qbf[qb + 24];
  }
  __syncthreads();  // halo staged

  // ---- QK: lane handles neighbors n = nn*16 + sub; 4 indep fma chains ----
  float sc[4];
  float pm = -1e30f;
#pragma unroll
  for (int nn = 0; nn < 4; ++nn) {
    const int n = nn * 16 + sub;
    float s = -1e30f;
    if (n < 49) {
      const int ky = (n * 147) >> 10, kx = n - ky * 7;  // n/7, n%7
      const u16* kr = &kv_[(hpbase + ky * 10 + kx) * 40];
      float dd[4];
#pragma unroll
      for (int c8 = 0; c8 < 4; ++c8) {
        const f16x8 kk = *(const f16x8*)&kr[c8 * 8];
        float d = 0.f;
#pragma unroll
        for (int j = 0; j < 8; ++j) d += (float)kk[j] * (float)qh[c8][j];
        dd[c8] = d;
      }
      s = ((dd[0] + dd[1]) + (dd[2] + dd[3])) * kInvTemp;
    }
    sc[nn] = s;
    pm = fmaxf(pm, s);
  }
  // softmax across the 16-lane px group
  pm = fmaxf(pm, __shfl_xor(pm, 1));
  pm = fmaxf(pm, __shfl_xor(pm, 2));
  pm = fmaxf(pm, __shfl_xor(pm, 4));
  pm = fmaxf(pm, __shfl_xor(pm, 8));
  float zs = 0.f;
#pragma unroll
  for (int nn = 0; nn < 4; ++nn) {
    const int n = nn * 16 + sub;
    const float e = __expf(sc[nn] - pm);  // invalid n: exp(-huge) = 0
    zs += e;
    if (n < 49) s_w[px][n] = e;  // same-wave producer/consumer
  }
  zs += __shfl_xor(zs, 1);
  zs += __shfl_xor(zs, 2);
  zs += __shfl_xor(zs, 4);
  zs += __shfl_xor(zs, 8);
  const float rinv = 1.0f / zs;

  // ---- PV: lane owns channels {2*sub, 2*sub+1}; even/odd-n chain pairs ----
  float oa0 = 0.f, oa1 = 0.f, ob0 = 0.f, ob1 = 0.f;
#pragma unroll
  for (int n = 0; n < 49; ++n) {
    const int ky = n / 7, kx = n % 7;  // compile-time
    const int hp = hpbase + ky * 10 + kx;
    const float wgt = s_w[px][n];  // 16-lane broadcast
    const u32 vv = *(const u32*)&kv_[4000 + hp * 40 + sub * 2];
    const f16x2 v2 = __builtin_bit_cast(f16x2, vv);
    if (n & 1) {
      ob0 += wgt * (float)v2[0];
      ob1 += wgt * (float)v2[1];
    } else {
      oa0 += wgt * (float)v2[0];
      oa1 += wgt * (float)v2[1];
    }
  }
  const float o0 = oa0 + ob0, o1 = oa1 + ob1;
  *(u32*)&att[((size_t)(b * kHW + gp)) * kC + h * 32 + sub * 2] =
      pack2h(o0 * rinv, o1 * rinv);
}

// ---------------------------------------------------------------------------
// FC GEMM: BM=32 x BN=32 -> 1152 blocks; As now pure uint4 copies from the
// f16 Wfc produced by qkv's side-task (halves fc W traffic, deletes cvt).
// ---------------------------------------------------------------------------
__global__ __launch_bounds__(256) void gemm_fc_kernel(
    const u16* __restrict__ att, const u16* __restrict__ wfch,
    const float* __restrict__ Res, float* __restrict__ Out) {
  __shared__ __align__(16) u16 As[32 * 64];  // Wfc rows (o)
  __shared__ __align__(16) u16 Bs[32 * 64];  // att rows (pixels)
  const int t = threadIdx.x;
  const int q0 = blockIdx.x * 32;  // pixel block (global over 4608)
  const int o0 = blockIdx.y * 32;
  const int bb = q0 / kHW, p0 = q0 - bb * kHW;  // 2304%32==0
  const int l = t & 63, w = t >> 6, wm = w >> 1, wn = w & 1;

  f32x4 acc = {0.f, 0.f, 0.f, 0.f};

  for (int kt = 0; kt < 4; ++kt) {
    const int k0 = kt * 64;
    if (kt) __syncthreads();
    {  // As <- f16 Wfc: 32 rows x 8 chunks = 256 tasks (pure copy)
      const int rr = t >> 3, ch = t & 7;
      const uint4 val =
          *(const uint4*)&wfch[(size_t)(o0 + rr) * kC + k0 + ch * 8];
      const int bo = (ch * 16) ^ ((rr & 7) << 4);
      *(uint4*)&As[rr * 64 + (bo >> 1)] = val;
    }
    {  // Bs <- att (f16): 32 rows x 8 uint4 = 256 tasks
      const int rr = t >> 3, ch = t & 7;
      const uint4 val =
          *(const uint4*)&att[(size_t)(q0 + rr) * kC + k0 + ch * 8];
      const int bo = (ch * 16) ^ ((rr & 7) << 4);
      *(uint4*)&Bs[rr * 64 + (bo >> 1)] = val;
    }
    __syncthreads();
#pragma unroll
    for (int ks = 0; ks < 2; ++ks) {
      const int bo = ks * 64 + ((l >> 4) << 4);
      const int rowa = wm * 16 + (l & 15);
      const f16x8 a =
          *(const f16x8*)&As[rowa * 64 + ((bo ^ ((rowa & 7) << 4)) >> 1)];
      const int rowb = wn * 16 + (l & 15);
      const f16x8 bfr =
          *(const f16x8*)&Bs[rowb * 64 + ((bo ^ ((rowb & 7) << 4)) >> 1)];
      acc = __builtin_amdgcn_mfma_f32_16x16x32_f16(a, bfr, acc, 0, 0, 0);
    }
  }
#pragma unroll
  for (int i = 0; i < 4; ++i) {
    const int o = o0 + wm * 16 + ((l >> 4) << 2) + i;
    const int p = p0 + wn * 16 + (l & 15);
    const size_t addr = ((size_t)(bb * kC + o)) * kHW + p;
    Out[addr] = acc[i] + Res[addr];
  }
}

}  // namespace

extern "C" void kernel_launch(void* const* d_in, const int* in_sizes, int n_in,
                              void* d_out, int out_size, void* d_ws,
                              size_t ws_size, hipStream_t stream) {
  const float* q = (const float*)d_in[0];
  const float* k = (const float*)d_in[1];
  const float* v = (const float*)d_in[2];
  const float* Wq = (const float*)d_in[3];
  const float* Wk = (const float*)d_in[4];
  const float* Wv = (const float*)d_in[5];
  const float* Wfc = (const float*)d_in[6];
  float* out = (float*)d_out;

  u16* ws16 = (u16*)d_ws;
  u16* kpad = ws16;
  u16* vpad = ws16 + KPAD_U16;
  u16* qbf = ws16 + 2 * KPAD_U16;
  u16* att = qbf + QBF_U16;
  u16* wfc16 = att + ATT_U16;

  gemm_qkv_kernel<<<dim3(kM / 32, kC / 64, 3), 256, 0, stream>>>(
      q, k, v, Wq, Wk, Wv, Wfc, qbf, kpad, vpad, wfc16);

  // 2304 blocks (8 blocks/CU co-resident): one (b,h,4x4 tile), XCD-decoded.
  attn4_kernel<<<dim3(2304), 256, 0, stream>>>(qbf, kpad, vpad, att);

  // 1152 blocks (4.5 waves/SIMD); Wfc read as f16 (no extra dispatch).
  gemm_fc_kernel<<<dim3(kM / 32, kC / 32), 256, 0, stream>>>(att, wfc16, q,
                                                             out);
}

// Round 23
// 33.996 us; speedup vs baseline: 1.1781x; 1.0009x over previous
//
#include <hip/hip_runtime.h>

typedef unsigned int u32;
typedef unsigned short u16;
typedef __attribute__((ext_vector_type(8))) _Float16 f16x8;
typedef __attribute__((ext_vector_type(2))) _Float16 f16x2;
typedef __attribute__((ext_vector_type(4))) float f32x4;

namespace {

constexpr int kH = 48, kW = 48, kHW = kH * kW;     // 2304
constexpr int kC = 256;
constexpr int kB = 2;
constexpr int kM = kB * kHW;                        // 4608 GEMM rows
constexpr int kPH = 54, kPW = 56, kPP = kPH * kPW;  // padded kv grid (3024)
constexpr float kInvTemp = 0.17677669529663687f;    // 1/sqrt(32)

constexpr size_t KPAD_U16 = (size_t)16 * kPP * 32;  // 1,548,288 u16 per mat
constexpr size_t QBF_U16 = (size_t)kM * kC;         // 1,179,648 u16
constexpr size_t ATT_U16 = (size_t)kM * kC;
// border zeroing: 720 border pixels/plane x 16 planes x 2 mats x 4 uint4
constexpr int kZeroTasks = 720 * 16 * 2 * 4;        // 92,160
constexpr int kZeroPerBlk = 54;                     // 1728 qkv blocks x 54 >= 92160
// Wfc f16 conversion side-task: 65536 floats = 8192 uint4 outputs
constexpr int kWfcTasks = 8192;                     // 1728 blocks x 5 >= 8192

__device__ __forceinline__ u32 pack2h(float lo, float hi) {
  return __builtin_bit_cast(u32, __builtin_amdgcn_cvt_pkrtz(lo, hi));
}
__device__ __forceinline__ u16 f2h(float f) {
  return __builtin_bit_cast(u16, (_Float16)f);
}
__device__ __forceinline__ float f4e(const float4 v, int i) {
  return (i == 0) ? v.x : (i == 1) ? v.y : (i == 2) ? v.z : v.w;
}

// ---------------------------------------------------------------------------
// Fused QKV GEMM, 32x64 tiles -> 1728 blocks (R7/R15-proven).
// Side-work: border zeroing + Wfc->f16 conversion (5 tasks/block, rides
// free; fc consumes it two dispatches later — no extra launch, which is
// what sank R16's serialized version of this idea: -2.6 vs +1.2).
// ---------------------------------------------------------------------------
__global__ __launch_bounds__(256) void gemm_qkv_kernel(
    const float* __restrict__ q, const float* __restrict__ k,
    const float* __restrict__ v, const float* __restrict__ Wq,
    const float* __restrict__ Wk, const float* __restrict__ Wv,
    const float* __restrict__ Wfc, u16* __restrict__ qbf,
    u16* __restrict__ kpad, u16* __restrict__ vpad, u16* __restrict__ wfc16) {
  __shared__ __align__(16) u16 As[32 * 64];
  __shared__ __align__(16) u16 Bs[64 * 64];
  const int t = threadIdx.x;
  const int bid = (blockIdx.z * 4 + blockIdx.y) * 144 + blockIdx.x;

  // ---- border zeroing (1.5 MB total across the 1728 blocks) ----
  {
    const int T = bid * kZeroPerBlk + t;
    if (t < kZeroPerBlk && T < kZeroTasks) {
      const int ch = T & 3, rest = T >> 2;  // rest < 23040
      const int pm = rest / 720, bi = rest - pm * 720;
      int y, x;
      if (bi < 336) {  // full rows 0,1,2,51,52,53
        const int r = bi / 56, c = bi - (bi / 56) * 56;
        y = (r < 3) ? r : 48 + r;
        x = c;
      } else {  // rows 3..50, cols {0,1,2,51..55}
        const int r = (bi - 336) >> 3, c = (bi - 336) & 7;
        y = 3 + r;
        x = (c < 3) ? c : c + 48;
      }
      u16* pb = (pm >= 16) ? vpad : kpad;
      const uint4 zz = {0u, 0u, 0u, 0u};
      *(uint4*)&pb[((size_t)(pm & 15) * kPP + y * kPW + x) * 32 + ch * 8] = zz;
    }
  }
  // ---- Wfc -> f16 (8192 uint4 tasks over 1728 blocks; threads 64..68) ----
  {
    const int j = t - 64;
    if (j >= 0 && j < 5) {
      const int T = bid * 5 + j;
      if (T < kWfcTasks) {
        const float4 a = *(const float4*)&Wfc[T * 8];
        const float4 bq = *(const float4*)&Wfc[T * 8 + 4];
        uint4 pk;
        pk.x = pack2h(a.x, a.y);
        pk.y = pack2h(a.z, a.w);
        pk.z = pack2h(bq.x, bq.y);
        pk.w = pack2h(bq.z, bq.w);
        *(uint4*)&wfc16[(size_t)T * 8] = pk;
      }
    }
  }

  const int z = blockIdx.z;
  const float* X = (z == 0) ? q : (z == 1) ? k : v;
  const float* Wm = (z == 0) ? Wq : (z == 1) ? Wk : Wv;
  const int m0 = blockIdx.x * 32, n0 = blockIdx.y * 64;
  const int bb = m0 / kHW, p0 = m0 - bb * kHW;  // 2304%32==0: no straddle
  const int l = t & 63, w = t >> 6, wm = w >> 1, wn = w & 1;
  const int mq = t & 7, kp = t >> 3;  // kp in [0,32): c-pair index

  f32x4 acc[2];
#pragma unroll
  for (int nf = 0; nf < 2; ++nf) acc[nf] = (f32x4){0.f, 0.f, 0.f, 0.f};

  for (int kt = 0; kt < 4; ++kt) {
    const int k0 = kt * 64;
    if (kt) __syncthreads();
    {
      const float* ab =
          X + ((size_t)(bb * kC + k0 + kp * 2)) * kHW + p0 + mq * 4;
      const float4 r0 = *(const float4*)(ab);
      const float4 r1 = *(const float4*)(ab + kHW);
#pragma unroll
      for (int i = 0; i < 4; ++i) {
        const int ml = mq * 4 + i;
        const u32 pk = pack2h(f4e(r0, i), f4e(r1, i));
        const int bo = (kp * 4) ^ ((ml & 7) << 4);
        *(u32*)&As[ml * 64 + (bo >> 1)] = pk;
      }
    }
#pragma unroll
    for (int j = 0; j < 4; ++j) {
      const int task2 = t + j * 256;
      const int rr = task2 >> 4, f4i = task2 & 15;
      const float4 val =
          *(const float4*)&Wm[(size_t)(n0 + rr) * kC + k0 + f4i * 4];
      uint2 pk;
      pk.x = pack2h(val.x, val.y);
      pk.y = pack2h(val.z, val.w);
      const int bo = (f4i * 8) ^ ((rr & 7) << 4);
      *(uint2*)&Bs[rr * 64 + (bo >> 1)] = pk;
    }
    __syncthreads();
#pragma unroll
    for (int ks = 0; ks < 2; ++ks) {
      const int bo = ks * 64 + ((l >> 4) << 4);
      const int rowa = wm * 16 + (l & 15);
      const f16x8 a =
          *(const f16x8*)&As[rowa * 64 + ((bo ^ ((rowa & 7) << 4)) >> 1)];
      f16x8 bfr[2];
#pragma unroll
      for (int nf = 0; nf < 2; ++nf) {
        const int row = wn * 32 + nf * 16 + (l & 15);
        bfr[nf] =
            *(const f16x8*)&Bs[row * 64 + ((bo ^ ((row & 7) << 4)) >> 1)];
      }
#pragma unroll
      for (int nf = 0; nf < 2; ++nf)
        acc[nf] = __builtin_amdgcn_mfma_f32_16x16x32_f16(a, bfr[nf], acc[nf],
                                                         0, 0, 0);
    }
  }

  u16* pd = (z == 1) ? kpad : vpad;
#pragma unroll
  for (int nf = 0; nf < 2; ++nf)
#pragma unroll
    for (int i = 0; i < 4; ++i) {
      const int m = m0 + wm * 16 + ((l >> 4) << 2) + i;
      const int o = n0 + wn * 32 + nf * 16 + (l & 15);
      const float val = acc[nf][i];
      if (z == 0) {
        qbf[(size_t)m * kC + o] = f2h(val);
      } else {
        const int p = m - bb * kHW;
        const int y = p / kW, x = p - (p / kW) * kW;
        pd[((size_t)(bb * 8 + (o >> 5)) * kPP + (y + 3) * kPW + (x + 3)) * 32 +
           (o & 31)] = f2h(val);
      }
    }
}

// ---------------------------------------------------------------------------
// Attention v4b (R15/R19-proven, verbatim): 2304 blocks, natural VGPR,
// narrow PV with even/odd-n chain pairs, ILP'd QK, XCD decode.
// ---------------------------------------------------------------------------
__global__ __launch_bounds__(256) void attn4_kernel(
    const u16* __restrict__ qbf, const u16* __restrict__ kpad,
    const u16* __restrict__ vpad, u16* __restrict__ att) {
  __shared__ __align__(16) u16 kv_[2 * 100 * 40];  // 16 KB: k then v halo
  __shared__ float s_w[16][52];                    // 3.3 KB softmax weights

  const int t = threadIdx.x;
  const int bid = blockIdx.x;
  const int g = bid & 7, i = bid >> 3;        // g = XCD slot, i in [0,288)
  const int bh = g * 2 + (i >= 144 ? 1 : 0);  // bh pair per XCD
  const int tile = (i >= 144) ? i - 144 : i;
  const int tyi = tile / 12, txi = tile - tyi * 12;
  const int y0 = tyi * 4, x0 = txi * 4;
  const int b = bh >> 3, h = bh & 7;
  const int px = t >> 4, sub = t & 15;  // 16 px x 16 lanes
  const int py = px >> 2, pxx = px & 3;
  const int gp = (y0 + py) * kW + (x0 + pxx);
  const int hpbase = py * 10 + pxx;

  // ---- stage k+v 10x10 halo: 800 uint4 tasks over 256 threads ----
  const size_t plane = (size_t)bh * kPP;
  for (int task = t; task < 800; task += 256) {
    const int mat = task >= 400;
    const int rem = task - mat * 400;
    const int hp = rem >> 2, c8 = rem & 3;
    const int hy = hp / 10, hx = hp - hy * 10;
    const size_t src = (plane + (y0 + hy) * kPW + (x0 + hx)) * 32 + c8 * 8;
    *(uint4*)&kv_[mat * 4000 + hp * 40 + c8 * 8] =
        *(const uint4*)&(mat ? vpad : kpad)[src];
  }
  // q: full 32 ch in f16 regs (redundant across the 16 lanes of a px; L1)
  f16x8 qh[4];
  {
    const size_t qb = ((size_t)(b * kHW + gp)) * kC + h * 32;
    qh[0] = *(const f16x8*)&qbf[qb + 0];
    qh[1] = *(const f16x8*)&qbf[qb + 8];
    qh[2] = *(const f16x8*)&qbf[qb + 16];
    qh[3] = *(const f16x8*)&qbf[qb + 24];
  }
  __syncthreads();  // halo staged

  // ---- QK: lane handles neighbors n = nn*16 + sub; 4 indep fma chains ----
  float sc[4];
  float pm = -1e30f;
#pragma unroll
  for (int nn = 0; nn < 4; ++nn) {
    const int n = nn * 16 + sub;
    float s = -1e30f;
    if (n < 49) {
      const int ky = (n * 147) >> 10, kx = n - ky * 7;  // n/7, n%7
      const u16* kr = &kv_[(hpbase + ky * 10 + kx) * 40];
      float dd[4];
#pragma unroll
      for (int c8 = 0; c8 < 4; ++c8) {
        const f16x8 kk = *(const f16x8*)&kr[c8 * 8];
        float d = 0.f;
#pragma unroll
        for (int j = 0; j < 8; ++j) d += (float)kk[j] * (float)qh[c8][j];
        dd[c8] = d;
      }
      s = ((dd[0] + dd[1]) + (dd[2] + dd[3])) * kInvTemp;
    }
    sc[nn] = s;
    pm = fmaxf(pm, s);
  }
  // softmax across the 16-lane px group
  pm = fmaxf(pm, __shfl_xor(pm, 1));
  pm = fmaxf(pm, __shfl_xor(pm, 2));
  pm = fmaxf(pm, __shfl_xor(pm, 4));
  pm = fmaxf(pm, __shfl_xor(pm, 8));
  float zs = 0.f;
#pragma unroll
  for (int nn = 0; nn < 4; ++nn) {
    const int n = nn * 16 + sub;
    const float e = __expf(sc[nn] - pm);  // invalid n: exp(-huge) = 0
    zs += e;
    if (n < 49) s_w[px][n] = e;  // same-wave producer/consumer
  }
  zs += __shfl_xor(zs, 1);
  zs += __shfl_xor(zs, 2);
  zs += __shfl_xor(zs, 4);
  zs += __shfl_xor(zs, 8);
  const float rinv = 1.0f / zs;

  // ---- PV: lane owns channels {2*sub, 2*sub+1}; even/odd-n chain pairs ----
  float oa0 = 0.f, oa1 = 0.f, ob0 = 0.f, ob1 = 0.f;
#pragma unroll
  for (int n = 0; n < 49; ++n) {
    const int ky = n / 7, kx = n % 7;  // compile-time
    const int hp = hpbase + ky * 10 + kx;
    const float wgt = s_w[px][n];  // 16-lane broadcast
    const u32 vv = *(const u32*)&kv_[4000 + hp * 40 + sub * 2];
    const f16x2 v2 = __builtin_bit_cast(f16x2, vv);
    if (n & 1) {
      ob0 += wgt * (float)v2[0];
      ob1 += wgt * (float)v2[1];
    } else {
      oa0 += wgt * (float)v2[0];
      oa1 += wgt * (float)v2[1];
    }
  }
  const float o0 = oa0 + ob0, o1 = oa1 + ob1;
  *(u32*)&att[((size_t)(b * kHW + gp)) * kC + h * 32 + sub * 2] =
      pack2h(o0 * rinv, o1 * rinv);
}

// ---------------------------------------------------------------------------
// FC GEMM: BM=32 x BN=32 -> 1152 blocks; As as pure uint4 copies from the
// f16 Wfc produced by qkv's side-task (halves fc W traffic, deletes cvt).
// ---------------------------------------------------------------------------
__global__ __launch_bounds__(256) void gemm_fc_kernel(
    const u16* __restrict__ att, const u16* __restrict__ wfch,
    const float* __restrict__ Res, float* __restrict__ Out) {
  __shared__ __align__(16) u16 As[32 * 64];  // Wfc rows (o)
  __shared__ __align__(16) u16 Bs[32 * 64];  // att rows (pixels)
  const int t = threadIdx.x;
  const int q0 = blockIdx.x * 32;  // pixel block (global over 4608)
  const int o0 = blockIdx.y * 32;
  const int bb = q0 / kHW, p0 = q0 - bb * kHW;  // 2304%32==0
  const int l = t & 63, w = t >> 6, wm = w >> 1, wn = w & 1;

  f32x4 acc = {0.f, 0.f, 0.f, 0.f};

  for (int kt = 0; kt < 4; ++kt) {
    const int k0 = kt * 64;
    if (kt) __syncthreads();
    {  // As <- f16 Wfc: 32 rows x 8 chunks = 256 tasks (pure copy)
      const int rr = t >> 3, ch = t & 7;
      const uint4 val =
          *(const uint4*)&wfch[(size_t)(o0 + rr) * kC + k0 + ch * 8];
      const int bo = (ch * 16) ^ ((rr & 7) << 4);
      *(uint4*)&As[rr * 64 + (bo >> 1)] = val;
    }
    {  // Bs <- att (f16): 32 rows x 8 uint4 = 256 tasks
      const int rr = t >> 3, ch = t & 7;
      const uint4 val =
          *(const uint4*)&att[(size_t)(q0 + rr) * kC + k0 + ch * 8];
      const int bo = (ch * 16) ^ ((rr & 7) << 4);
      *(uint4*)&Bs[rr * 64 + (bo >> 1)] = val;
    }
    __syncthreads();
#pragma unroll
    for (int ks = 0; ks < 2; ++ks) {
      const int bo = ks * 64 + ((l >> 4) << 4);
      const int rowa = wm * 16 + (l & 15);
      const f16x8 a =
          *(const f16x8*)&As[rowa * 64 + ((bo ^ ((rowa & 7) << 4)) >> 1)];
      const int rowb = wn * 16 + (l & 15);
      const f16x8 bfr =
          *(const f16x8*)&Bs[rowb * 64 + ((bo ^ ((rowb & 7) << 4)) >> 1)];
      acc = __builtin_amdgcn_mfma_f32_16x16x32_f16(a, bfr, acc, 0, 0, 0);
    }
  }
#pragma unroll
  for (int i = 0; i < 4; ++i) {
    const int o = o0 + wm * 16 + ((l >> 4) << 2) + i;
    const int p = p0 + wn * 16 + (l & 15);
    const size_t addr = ((size_t)(bb * kC + o)) * kHW + p;
    Out[addr] = acc[i] + Res[addr];
  }
}

}  // namespace

extern "C" void kernel_launch(void* const* d_in, const int* in_sizes, int n_in,
                              void* d_out, int out_size, void* d_ws,
                              size_t ws_size, hipStream_t stream) {
  const float* q = (const float*)d_in[0];
  const float* k = (const float*)d_in[1];
  const float* v = (const float*)d_in[2];
  const float* Wq = (const float*)d_in[3];
  const float* Wk = (const float*)d_in[4];
  const float* Wv = (const float*)d_in[5];
  const float* Wfc = (const float*)d_in[6];
  float* out = (float*)d_out;

  u16* ws16 = (u16*)d_ws;
  u16* kpad = ws16;
  u16* vpad = ws16 + KPAD_U16;
  u16* qbf = ws16 + 2 * KPAD_U16;
  u16* att = qbf + QBF_U16;
  u16* wfc16 = att + ATT_U16;

  gemm_qkv_kernel<<<dim3(kM / 32, kC / 64, 3), 256, 0, stream>>>(
      q, k, v, Wq, Wk, Wv, Wfc, qbf, kpad, vpad, wfc16);

  // 2304 blocks (8 blocks/CU co-resident): one (b,h,4x4 tile), XCD-decoded.
  attn4_kernel<<<dim3(2304), 256, 0, stream>>>(qbf, kpad, vpad, att);

  // 1152 blocks (4.5 waves/SIMD); Wfc read as f16 (no extra dispatch).
  gemm_fc_kernel<<<dim3(kM / 32, kC / 32), 256, 0, stream>>>(att, wfc16, q,
                                                             out);
}